// Round 4
// baseline (57.467 us; speedup 1.0000x reference)
//
#include <hip/hip_runtime.h>

#define NB 2048
#define NC 16
#define ND 256
#define OUTW 353
#define THRED 0.8f
#define SIM_PER_XCD 128      // sim-pair blocks per XCD (2 b each) -> 1024 total
#define NEIGH_PER_XCD 1024   // neigh blocks per XCD (4 rows each) -> 8192 total
#define PER_XCD 1152
#define NBLK 9216

typedef short bf16x8 __attribute__((ext_vector_type(8)));
typedef float f32x4 __attribute__((ext_vector_type(4)));
typedef float f32x4a __attribute__((ext_vector_type(4), aligned(4)));

__device__ __forceinline__ unsigned short f2bf(float x) {   // RNE
    unsigned int u = __float_as_uint(x);
    u += 0x7FFFu + ((u >> 16) & 1u);
    return (unsigned short)(u >> 16);
}

__device__ __forceinline__ bf16x8 cvt8(const float4& a, const float4& b) {
    bf16x8 r;
    r[0] = (short)f2bf(a.x); r[1] = (short)f2bf(a.y);
    r[2] = (short)f2bf(a.z); r[3] = (short)f2bf(a.w);
    r[4] = (short)f2bf(b.x); r[5] = (short)f2bf(b.y);
    r[6] = (short)f2bf(b.z); r[7] = (short)f2bf(b.w);
    return r;
}

__global__ __launch_bounds__(256) void fused_kernel(const float* __restrict__ e,
                                                    const int* __restrict__ nm,
                                                    float* __restrict__ out) {
    __shared__ float lsum[4][16];

    const int xcd = blockIdx.x & 7;
    const int idx = blockIdx.x >> 3;          // 0..1151, contiguous work per XCD
    const int w   = threadIdx.x >> 6;
    const int l   = threadIdx.x & 63;

    if (idx >= SIM_PER_XCD) {
        // ================= NEIGH role: 1 wave per output row =================
        const int nrow = (xcd * NEIGH_PER_XCD + (idx - SIM_PER_XCD)) * 4 + w;
        const int b = nrow >> 4, c = nrow & 15;

        // cumulative 0/1 masks — uniform across the wave (c fixed)
        float a1 = (b - 1 >= 0) ? (float)nm[(b - 1) * NC + c] : 0.f;
        float a2 = (b - 2 >= 0) ? (float)nm[(b - 2) * NC + c] : 0.f;
        float a3 = (b - 3 >= 0) ? (float)nm[(b - 3) * NC + c] : 0.f;
        float r0 = (float)nm[b * NC + c];
        float r1 = (b + 1 < NB) ? (float)nm[(b + 1) * NC + c] : 0.f;
        float r2 = (b + 2 < NB) ? (float)nm[(b + 2) * NC + c] : 0.f;
        float mk[6];
        mk[0] = a1; mk[1] = a1 * a2; mk[2] = a1 * a2 * a3;
        mk[3] = r0; mk[4] = r0 * r1; mk[5] = r0 * r1 * r2;
        const int offs[6] = {-1, -2, -3, 1, 2, 3};

        f32x4 acc = (f32x4){0.f, 0.f, 0.f, 0.f};
#pragma unroll
        for (int p = 0; p < 6; ++p) {
            const int gb = b + offs[p];
            if (mk[p] != 0.f && gb >= 0 && gb < NB) {     // wave-uniform
                const float4 v = *reinterpret_cast<const float4*>(
                    e + ((size_t)gb * NC + c) * ND + l * 4);
                acc[0] = fmaf(mk[p], v.x, acc[0]);
                acc[1] = fmaf(mk[p], v.y, acc[1]);
                acc[2] = fmaf(mk[p], v.z, acc[2]);
                acc[3] = fmaf(mk[p], v.w, acc[3]);
            }
        }
        const float s6 = 1.0f / 6.0f;
        f32x4 r;
        r[0] = acc[0] * s6; r[1] = acc[1] * s6; r[2] = acc[2] * s6; r[3] = acc[3] * s6;
        *reinterpret_cast<f32x4a*>(out + (size_t)nrow * OUTW + l * 4) = r;
        return;
    }

    // ================= SIM role: 2 waves per b (left/right 3 p's) =================
    const int simpair = xcd * SIM_PER_XCD + idx;
    const int b    = simpair * 2 + (w >> 1);
    const int side = w & 1;                   // 0 = left (-1,-2,-3), 1 = right (+1,+2,+3)
    const int col  = l & 15, hi = l >> 4;
    const int koff = hi * 8;

    // per-col cumulative masks for this side's 3 shifts
    float mk[3];
    if (side == 0) {
        float a1 = (b - 1 >= 0) ? (float)nm[(b - 1) * NC + col] : 0.f;
        float a2 = (b - 2 >= 0) ? (float)nm[(b - 2) * NC + col] : 0.f;
        float a3 = (b - 3 >= 0) ? (float)nm[(b - 3) * NC + col] : 0.f;
        mk[0] = a1; mk[1] = a1 * a2; mk[2] = a1 * a2 * a3;
    } else {
        float a0 = (float)nm[b * NC + col];
        float a1 = (b + 1 < NB) ? (float)nm[(b + 1) * NC + col] : 0.f;
        float a2 = (b + 2 < NB) ? (float)nm[(b + 2) * NC + col] : 0.f;
        mk[0] = a0; mk[1] = a0 * a1; mk[2] = a0 * a1 * a2;
    }

    // own tile -> A-frags + exact fp32 norm
    const float* rp0 = e + ((size_t)b * NC + col) * ND + koff;
    float4 s[16];
#pragma unroll
    for (int c = 0; c < 8; ++c) {
        s[2 * c]     = *reinterpret_cast<const float4*>(rp0 + c * 32);
        s[2 * c + 1] = *reinterpret_cast<const float4*>(rp0 + c * 32 + 4);
    }
    bf16x8 af[8];
    float ssq = 0.f;
#pragma unroll
    for (int c = 0; c < 8; ++c) {
        const float4 a = s[2 * c], bb = s[2 * c + 1];
        af[c] = cvt8(a, bb);
        ssq = fmaf(a.x, a.x, ssq);  ssq = fmaf(a.y, a.y, ssq);
        ssq = fmaf(a.z, a.z, ssq);  ssq = fmaf(a.w, a.w, ssq);
        ssq = fmaf(bb.x, bb.x, ssq); ssq = fmaf(bb.y, bb.y, ssq);
        ssq = fmaf(bb.z, bb.z, ssq); ssq = fmaf(bb.w, bb.w, ssq);
    }
    ssq += __shfl_xor(ssq, 16, 64);
    ssq += __shfl_xor(ssq, 32, 64);
    const float nrm_own = sqrtf(ssq);

    f32x4 acc[3];
    float nbn[3];
#pragma unroll
    for (int pp = 0; pp < 3; ++pp) {
        acc[pp] = (f32x4){0.f, 0.f, 0.f, 0.f};
        nbn[pp] = 0.f;
        const int gb = b + (side ? (pp + 1) : -(pp + 1));
        if (gb >= 0 && gb < NB) {
            const float* rp = e + ((size_t)gb * NC + col) * ND + koff;
#pragma unroll
            for (int c = 0; c < 8; ++c) {
                s[2 * c]     = *reinterpret_cast<const float4*>(rp + c * 32);
                s[2 * c + 1] = *reinterpret_cast<const float4*>(rp + c * 32 + 4);
            }
            float sq = 0.f;
#pragma unroll
            for (int c = 0; c < 8; ++c) {
                const float4 a = s[2 * c], bb = s[2 * c + 1];
                bf16x8 bf = cvt8(a, bb);
                acc[pp] = __builtin_amdgcn_mfma_f32_16x16x32_bf16(af[c], bf, acc[pp], 0, 0, 0);
                sq = fmaf(a.x, a.x, sq);  sq = fmaf(a.y, a.y, sq);
                sq = fmaf(a.z, a.z, sq);  sq = fmaf(a.w, a.w, sq);
                sq = fmaf(bb.x, bb.x, sq); sq = fmaf(bb.y, bb.y, sq);
                sq = fmaf(bb.z, bb.z, sq); sq = fmaf(bb.w, bb.w, sq);
            }
            sq += __shfl_xor(sq, 16, 64);
            sq += __shfl_xor(sq, 32, 64);
            nbn[pp] = sqrtf(sq);
        }
    }

    float na[4];
#pragma unroll
    for (int r = 0; r < 4; ++r) na[r] = __shfl(nrm_own, hi * 4 + r, 16);

    float sim[3][4];
    float rowsum[4] = {0.f, 0.f, 0.f, 0.f};
#pragma unroll
    for (int pp = 0; pp < 3; ++pp) {
        const bool mv = (mk[pp] != 0.f);
#pragma unroll
        for (int r = 0; r < 4; ++r) {
            float qd = acc[pp][r] / fmaxf(na[r] * nbn[pp], 1e-8f);
            float sv = (mv && qd > THRED) ? fminf(qd, 1.f) : 0.f;
            sim[pp][r] = sv;
            rowsum[r] += sv;
        }
    }
#pragma unroll
    for (int r = 0; r < 4; ++r) {
#pragma unroll
        for (int o = 1; o < 16; o <<= 1) rowsum[r] += __shfl_xor(rowsum[r], o, 16);
    }

    // combine left+right row sums across the wave pair
    if (col == 0) {
#pragma unroll
        for (int r = 0; r < 4; ++r) lsum[w][hi * 4 + r] = rowsum[r];
    }
    __syncthreads();

    const int p_base = side * 3;
#pragma unroll
    for (int r = 0; r < 4; ++r) {
        const float tot = rowsum[r] + lsum[w ^ 1][hi * 4 + r];
        const float inv = 1.0f / fmaxf(tot + 1.0f, 1e-12f);
        float* orow = out + (size_t)(b * NC + hi * 4 + r) * OUTW;
#pragma unroll
        for (int pp = 0; pp < 3; ++pp)
            orow[ND + (p_base + pp) * NC + col] = sim[pp][r] * inv;
        if (side == 0 && col == 0) orow[ND + 96] = inv;
    }
}

extern "C" void kernel_launch(void* const* d_in, const int* in_sizes, int n_in,
                              void* d_out, int out_size, void* d_ws, size_t ws_size,
                              hipStream_t stream) {
    const float* e = (const float*)d_in[0];
    const int* nmv = (const int*)d_in[1];
    float* out     = (float*)d_out;
    fused_kernel<<<NBLK, 256, 0, stream>>>(e, nmv, out);
}